// Round 18
// baseline (138.492 us; speedup 1.0000x reference)
//
#include <hip/hip_runtime.h>
#include <math.h>

// LinearAttention: B=16, C=256, H=W=64 (N=4096), 8 heads x 32 dim.
// R1..R12: pipeline fusion ladder (299 -> 133.8us).
// R15: acc reuse + shared rinv. BEST = 132.0us.
// R13/R14/R16: structural variants regressed; R17 restored R15.
// R18: k_qfinal pushed under the 64-total-reg occupancy cliff (m69:
//      waves/SIMD halve at {64,128,256}; unified VGPR+AGPR file):
//      wave tile 32->16 rows (acc 16 AGPR), 1024 thr / 16 waves,
//      __launch_bounds__(1024,8) pins the 64 budget (inherent ~61).
//      Softmax max/sum exchanged across wave pairs via LDS red2.
//      kvctx/fold/prep identical to R15.

#define B_ 16
#define C_ 256
#define N_ 4096
#define SCALE_ 0.17677669529663687f
#define EPS_ 1e-12f

typedef __attribute__((ext_vector_type(8))) short bf16x8;
typedef __attribute__((ext_vector_type(4))) float f32x4;

__device__ __forceinline__ ushort f2bf(float f) {
    union { float f; uint u; } x; x.f = f;
    uint r = (x.u + 0x7FFFu + ((x.u >> 16) & 1u)) >> 16;
    return (ushort)r;
}
__device__ __forceinline__ float bf2f(ushort s) {
    union { uint u; float f; } x; x.u = ((uint)s) << 16;
    return x.f;
}

// ---------------- K1: W' = w_qkv * g1 -> bf16 ----------------
__global__ __launch_bounds__(256) void k_prep(const float* __restrict__ w_qkv,
                                              const float* __restrict__ g1,
                                              ushort* __restrict__ Wp) {
    int o = blockIdx.x, c = threadIdx.x;
    Wp[(size_t)o * 256 + c] = f2bf(w_qkv[(size_t)o * 256 + c] * g1[c]);
}

// ---------------- K2: fused rnorm + kv-GEMM + exp + ctx partial -----------
// (R15, unchanged) grid (32,16), 512 thr. Exports rinv[b][n].
__global__ __launch_bounds__(512) void k_kvctx(const ushort* __restrict__ Wp,
                                               const float* __restrict__ x,
                                               float* __restrict__ ctxp,
                                               float* __restrict__ sums_p,
                                               float* __restrict__ rinvws) {
    extern __shared__ char lds[];
    ushort (*Asub)[40] = (ushort(*)[40])lds;          // 20480 B
    char* BQ = lds + 20480;                           // 65536 B
    char* P  = lds + 86016;                           // 65536 B
    float* sspA  = (float*)(lds + 151552);            //  2048 B
    float* rinvA = (float*)(lds + 153600);            //   512 B
    const int b = blockIdx.y, s = blockIdx.x;
    const int col0 = s * 128;
    const int t = threadIdx.x, l = t & 63, w = t >> 6;
    const int lr = l & 15, grp = l >> 4;
    const int wn = w & 3, wo = w >> 2;
    const float* xb = x + (size_t)b * C_ * N_ + col0;

    {   // prologue A: per-column sumsq (coalesced: lane = column)
        int col = t & 127, rg = t >> 7;
        float ss = 0.f;
        #pragma unroll 8
        for (int i = 0; i < 64; ++i) {
            float v = xb[(size_t)(rg * 64 + i) * N_ + col];
            ss += v * v;
        }
        sspA[rg * 128 + col] = ss;
    }
    __syncthreads();
    if (t < 128) {
        float rv = 16.f / fmaxf(sqrtf(sspA[t] + sspA[128 + t] + sspA[256 + t] + sspA[384 + t]), EPS_);
        rinvA[t] = rv;
        rinvws[(size_t)b * N_ + col0 + t] = rv;
    }
    __syncthreads();
    {   // prologue B: xn = bf16(x*rinv) -> BQ[col][c], byte ^= (col&7)<<4
        int col = t & 127, rg = t >> 7;
        float rv = rinvA[col];
        uint sw = (uint)((col & 7) << 4);
        #pragma unroll
        for (int i = 0; i < 16; ++i) {
            int c = rg * 64 + i * 4;
            uint2 pk;
            pk.x = (uint)f2bf(xb[(size_t)c * N_ + col] * rv)
                 | ((uint)f2bf(xb[(size_t)(c + 1) * N_ + col] * rv) << 16);
            pk.y = (uint)f2bf(xb[(size_t)(c + 2) * N_ + col] * rv)
                 | ((uint)f2bf(xb[(size_t)(c + 3) * N_ + col] * rv) << 16);
            *(uint2*)(BQ + (((uint)(col * 512 + c * 2)) ^ sw)) = pk;
        }
    }

    #pragma unroll
    for (int p = 0; p < 2; ++p) {
        f32x4 acc[2][8] = {};
        for (int k0 = 0; k0 < 256; k0 += 32) {
            {   // stage Wkv o-rows (p=0: Wp 256.., p=1: Wp 512..)
                int r = t >> 1, ko = (t & 1) * 16;
                const uint4* sa = (const uint4*)(Wp + (size_t)(256 + p * 256 + r) * 256 + k0 + ko);
                *(uint4*)&Asub[r][ko]     = sa[0];
                *(uint4*)&Asub[r][ko + 8] = sa[1];
            }
            __syncthreads();   // first iter also fences prologue BQ writes
            bf16x8 ax[2], bw[8];
            #pragma unroll
            for (int m = 0; m < 2; ++m) {
                int row = wn * 32 + m * 16 + lr;
                uint off = (uint)(row * 512 + (k0 + grp * 8) * 2) ^ (uint)((row & 7) << 4);
                ax[m] = *(const bf16x8*)(BQ + off);
            }
            #pragma unroll
            for (int nf = 0; nf < 8; ++nf)
                bw[nf] = *(const bf16x8*)&Asub[wo * 128 + nf * 16 + lr][grp * 8];
            #pragma unroll
            for (int m = 0; m < 2; ++m)
                #pragma unroll
                for (int nf = 0; nf < 8; ++nf)
                    acc[m][nf] = __builtin_amdgcn_mfma_f32_16x16x32_bf16(ax[m], bw[nf], acc[m][nf], 0, 0, 0);
            __syncthreads();
        }
        if (p == 0) {
            // P[d][n] = bf16(exp(logit)), rows 256B, byte ^= (d&7)<<4
            #pragma unroll
            for (int nf = 0; nf < 8; ++nf) {
                int d = wo * 128 + nf * 16 + lr;
                uint sw = (uint)((d & 7) << 4);
                #pragma unroll
                for (int m = 0; m < 2; ++m) {
                    int n0 = wn * 32 + m * 16 + grp * 4;
                    uint2 pk;
                    pk.x = (uint)f2bf(__expf(acc[m][nf][0])) | ((uint)f2bf(__expf(acc[m][nf][1])) << 16);
                    pk.y = (uint)f2bf(__expf(acc[m][nf][2])) | ((uint)f2bf(__expf(acc[m][nf][3])) << 16);
                    *(uint2*)(P + (((uint)(d * 256 + n0 * 2)) ^ sw)) = pk;
                }
            }
        } else {
            // V[e][n] overlaid onto BQ (xn dead after pass-1 trailing barrier)
            #pragma unroll
            for (int nf = 0; nf < 8; ++nf) {
                int e = wo * 128 + nf * 16 + lr;
                uint sw = (uint)((e & 7) << 4);
                #pragma unroll
                for (int m = 0; m < 2; ++m) {
                    int n0 = wn * 32 + m * 16 + grp * 4;
                    uint2 pk;
                    pk.x = (uint)f2bf(acc[m][nf][0]) | ((uint)f2bf(acc[m][nf][1]) << 16);
                    pk.y = (uint)f2bf(acc[m][nf][2]) | ((uint)f2bf(acc[m][nf][3]) << 16);
                    *(uint2*)(BQ + (((uint)(e * 256 + n0 * 2)) ^ sw)) = pk;
                }
            }
        }
    }
    __syncthreads();   // P and V fully visible

    // per-head ctx: wave = head
    const int h = w;
    f32x4 c3[2][2] = {};
    f32x4 cS[2] = {};
    bf16x8 ones;
    #pragma unroll
    for (int j = 0; j < 8; ++j) ones[j] = (short)0x3F80;   // bf16 1.0
    #pragma unroll
    for (int ks = 0; ks < 4; ++ks) {
        int n0 = ks * 32 + grp * 8;
        bf16x8 pA[2], vB[2];
        #pragma unroll
        for (int df = 0; df < 2; ++df) {
            int d = h * 32 + df * 16 + lr;
            pA[df] = *(const bf16x8*)(P + (((uint)(d * 256 + n0 * 2)) ^ ((uint)((d & 7) << 4))));
        }
        #pragma unroll
        for (int ef = 0; ef < 2; ++ef) {
            int e = h * 32 + ef * 16 + lr;
            vB[ef] = *(const bf16x8*)(BQ + (((uint)(e * 256 + n0 * 2)) ^ ((uint)((e & 7) << 4))));
        }
        #pragma unroll
        for (int df = 0; df < 2; ++df) {
            #pragma unroll
            for (int ef = 0; ef < 2; ++ef)
                c3[df][ef] = __builtin_amdgcn_mfma_f32_16x16x32_bf16(pA[df], vB[ef], c3[df][ef], 0, 0, 0);
            cS[df] = __builtin_amdgcn_mfma_f32_16x16x32_bf16(pA[df], ones, cS[df], 0, 0, 0);
        }
    }
    int bh = b * 8 + h;
    size_t base = ((size_t)s * 128 + bh) * 32;
    #pragma unroll
    for (int df = 0; df < 2; ++df) {
        #pragma unroll
        for (int ef = 0; ef < 2; ++ef)
            #pragma unroll
            for (int r = 0; r < 4; ++r)
                ctxp[(base + df * 16 + grp * 4 + r) * 32 + ef * 16 + lr] = c3[df][ef][r];
        if (lr == 0)
            #pragma unroll
            for (int r = 0; r < 4; ++r)
                sums_p[base + df * 16 + grp * 4 + r] = cS[df][r];
    }
}

// ---------------- K3: M[b][o][h*32+d] = SCALE/stot[d] * sum_e w_out.ctx ----
__global__ __launch_bounds__(256) void k_fold(const float* __restrict__ w_out,
                                              const float* __restrict__ ctxp,
                                              const float* __restrict__ sums_p,
                                              ushort* __restrict__ M) {
    __shared__ float cn[32][33];
    __shared__ float sinv[32];
    int bh = blockIdx.x;
    int b = bh >> 3, h = bh & 7;
    int t = threadIdx.x;
    if (t < 32) {
        float st = 0.f;
        #pragma unroll 8
        for (int s = 0; s < 32; ++s) st += sums_p[(size_t)(s * 128 + bh) * 32 + t];
        sinv[t] = SCALE_ / st;
    }
    #pragma unroll
    for (int i = t; i < 1024; i += 256) {
        int d = i >> 5, e = i & 31;
        float cv = 0.f;
        #pragma unroll 8
        for (int s = 0; s < 32; ++s)
            cv += ctxp[((size_t)(s * 128 + bh) * 32 + d) * 32 + e];
        cn[e][d] = cv;
    }
    __syncthreads();
    float wreg[32];
    const float* wr = w_out + (size_t)t * 256 + h * 32;
    #pragma unroll
    for (int e = 0; e < 32; e += 4) {
        float4 wv = *(const float4*)&wr[e];
        wreg[e] = wv.x; wreg[e + 1] = wv.y; wreg[e + 2] = wv.z; wreg[e + 3] = wv.w;
    }
    float acc[32] = {};
    #pragma unroll
    for (int e = 0; e < 32; ++e) {
        float we = wreg[e];
        #pragma unroll
        for (int d = 0; d < 32; ++d) acc[d] += we * cn[e][d];
    }
    ushort* Mrow = M + ((size_t)b * 256 + t) * 256 + h * 32;
    #pragma unroll
    for (int d = 0; d < 32; ++d) Mrow[d] = f2bf(acc[d] * sinv[d]);
}

// ---------------- K4: fused q-GEMM + softmax + M@q + epilogue -------------
// grid (64 coltiles, 16 b), 1024 threads = 16 waves; wave = 16 out-rows.
// Head h = w>>1 spans wave pair {2h, 2h+1}: softmax max/sum exchanged
// via red2 LDS. acc = 16 AGPR; launch_bounds(1024,8) pins 64-reg budget.
__global__ __launch_bounds__(1024, 8) void k_qfinal(const ushort* __restrict__ Wp,
                                                    const ushort* __restrict__ M,
                                                    const float* __restrict__ b_out,
                                                    const float* __restrict__ g2,
                                                    const float* __restrict__ x,
                                                    const float* __restrict__ rinvws,
                                                    float* __restrict__ out) {
    __shared__ __align__(16) char shmem[34816];  // BQ (32768B) then OUT overlay
    __shared__ float red2[2][16][64];            // pmax/psum, then ssq reuse
    __shared__ float rinvq[64];
    ushort* BQ = (ushort*)shmem;    // swizzled: byte = (row*512+k*2) ^ ((row&7)<<4)
    float*  OUT = (float*)shmem;    // [128][68] f32 chunk buffer
    const int b = blockIdx.y, col0 = blockIdx.x * 64;
    const int t = threadIdx.x, l = t & 63, w = t >> 6;   // w: 0..15
    const int lr = l & 15, grp = l >> 4;
    const float* xb2 = x + (size_t)b * C_ * N_;

    if (t < 64) rinvq[t] = rinvws[(size_t)b * N_ + col0 + t];
    __syncthreads();
    {   // prologue: xn = bf16(x*rinv) -> BQ (each thread 16 channels)
        int col = t & 63, rg = t >> 6;
        float rv = rinvq[col];
        uint sw = (uint)((col & 7) << 4);
        #pragma unroll
        for (int i = 0; i < 4; ++i) {
            int c = rg * 16 + i * 4;
            uint2 pk;
            pk.x = (uint)f2bf(xb2[(size_t)c * N_ + col0 + col] * rv)
                 | ((uint)f2bf(xb2[(size_t)(c + 1) * N_ + col0 + col] * rv) << 16);
            pk.y = (uint)f2bf(xb2[(size_t)(c + 2) * N_ + col0 + col] * rv)
                 | ((uint)f2bf(xb2[(size_t)(c + 3) * N_ + col0 + col] * rv) << 16);
            *(uint2*)((char*)BQ + (((uint)(col * 512 + c * 2)) ^ sw)) = pk;
        }
    }
    __syncthreads();

    // ---- GEMM1: q = Wq @ xn (wave w -> rows w*16..w*16+15) ----
    f32x4 acc[4] = {};
    for (int k0 = 0; k0 < 256; k0 += 32) {
        bf16x8 af, bf[4];
        af = *(const bf16x8*)(Wp + (size_t)(w * 16 + lr) * 256 + k0 + grp * 8);
        #pragma unroll
        for (int n = 0; n < 4; ++n) {
            int row = n * 16 + lr;
            uint off = (uint)(row * 512 + (k0 + grp * 8) * 2) ^ (uint)((row & 7) << 4);
            bf[n] = *(const bf16x8*)((const char*)BQ + off);
        }
        #pragma unroll
        for (int n = 0; n < 4; ++n)
            acc[n] = __builtin_amdgcn_mfma_f32_16x16x32_bf16(af, bf[n], acc[n], 0, 0, 0);
    }
    __syncthreads();   // all GEMM1 reads of BQ (xn) complete

    // ---- softmax over d (head = w>>1 spans wave pair): 3 phases ----
    // phase 1: wave-partial max per column -> red2[0][w][cl]
    #pragma unroll
    for (int n = 0; n < 4; ++n) {
        float mx = fmaxf(fmaxf(acc[n][0], acc[n][1]), fmaxf(acc[n][2], acc[n][3]));
        mx = fmaxf(mx, __shfl_xor(mx, 16));
        mx = fmaxf(mx, __shfl_xor(mx, 32));
        if (grp == 0) red2[0][w][n * 16 + lr] = mx;
    }
    __syncthreads();
    // phase 2: full max, exp in place, wave-partial sum -> red2[1][w][cl]
    #pragma unroll
    for (int n = 0; n < 4; ++n) {
        int cl = n * 16 + lr;
        float mx = fmaxf(red2[0][w][cl], red2[0][w ^ 1][cl]);
        float s = 0.f;
        #pragma unroll
        for (int r = 0; r < 4; ++r) {
            acc[n][r] = __expf(acc[n][r] - mx);
            s += acc[n][r];
        }
        s += __shfl_xor(s, 16); s += __shfl_xor(s, 32);
        if (grp == 0) red2[1][w][cl] = s;
    }
    __syncthreads();
    // phase 3: normalize, overlay q into BQ ([col][d] swizzled)
    #pragma unroll
    for (int n = 0; n < 4; ++n) {
        int cl = n * 16 + lr;
        float inv = 1.f / (red2[1][w][cl] + red2[1][w ^ 1][cl]);
        int d = w * 16 + grp * 4;
        uint2 pk;
        pk.x = (uint)f2bf(acc[n][0] * inv) | ((uint)f2bf(acc[n][1] * inv) << 16);
        pk.y = (uint)f2bf(acc[n][2] * inv) | ((uint)f2bf(acc[n][3] * inv) << 16);
        uint off = (uint)(cl * 512 + d * 2) ^ (uint)((cl & 7) << 4);
        *(uint2*)((char*)BQ + off) = pk;
    }
    __syncthreads();   // all waves' q visible

    // ---- GEMM2: out = M @ q (REUSES acc registers) ----
    #pragma unroll
    for (int n = 0; n < 4; ++n)
        acc[n] = f32x4{0.f, 0.f, 0.f, 0.f};
    const ushort* Mb = M + (size_t)b * 256 * 256;
    for (int k0 = 0; k0 < 256; k0 += 32) {
        bf16x8 af, bq[4];
        af = *(const bf16x8*)(Mb + (size_t)(w * 16 + lr) * 256 + k0 + grp * 8);
        #pragma unroll
        for (int n = 0; n < 4; ++n) {
            int row = n * 16 + lr;
            uint off = (uint)(row * 512 + (k0 + grp * 8) * 2) ^ (uint)((row & 7) << 4);
            bq[n] = *(const bf16x8*)((const char*)BQ + off);
        }
        #pragma unroll
        for (int n = 0; n < 4; ++n)
            acc[n] = __builtin_amdgcn_mfma_f32_16x16x32_bf16(af, bq[n], acc[n], 0, 0, 0);
    }

    // ---- epilogue: +b_out, column ssq over 256 rows, scale ----
    __syncthreads();   // BQ reads done (OUT overlay next); red2 reads done
    #pragma unroll
    for (int n = 0; n < 4; ++n) {
        float local = 0.f;
        int obase = w * 16 + grp * 4;
        #pragma unroll
        for (int r = 0; r < 4; ++r) {
            float f = acc[n][r] + b_out[obase + r];
            acc[n][r] = f;
            local += f * f;
        }
        local += __shfl_xor(local, 16);
        local += __shfl_xor(local, 32);
        if (grp == 0) red2[0][w][n * 16 + lr] = local;
    }
    __syncthreads();
    #pragma unroll
    for (int n = 0; n < 4; ++n) {
        int cl = n * 16 + lr;
        float tot = 0.f;
        #pragma unroll
        for (int ww = 0; ww < 16; ++ww) tot += red2[0][ww][cl];
        float rs = 16.f / fmaxf(sqrtf(tot), EPS_);
        int obase = w * 16 + grp * 4;
        #pragma unroll
        for (int r = 0; r < 4; ++r)
            acc[n][r] *= rs * g2[obase + r];
    }
    float* ob = out + (size_t)b * C_ * N_;
    const int chunk = w >> 3;
    #pragma unroll
    for (int ch = 0; ch < 2; ++ch) {
        if (chunk == ch) {   // waves ch*8..ch*8+7 deposit rows 0..127 of chunk
            #pragma unroll
            for (int n = 0; n < 4; ++n) {
                int cl = n * 16 + lr;
                int rbase = (w & 7) * 16 + grp * 4;
                #pragma unroll
                for (int r = 0; r < 4; ++r)
                    OUT[(rbase + r) * 68 + cl] = acc[n][r];
            }
        }
        __syncthreads();
        // stream out 128 rows: lane=column float4 (256B contiguous per row)
        #pragma unroll
        for (int i = 0; i < 2; ++i) {
            int rowl = i * 64 + (t >> 4);
            int grow = ch * 128 + rowl;
            float4 v = *(float4*)&OUT[rowl * 68 + (t & 15) * 4];
            float4 xr = *(const float4*)&xb2[(size_t)grow * N_ + col0 + (t & 15) * 4];
            v.x += xr.x; v.y += xr.y; v.z += xr.z; v.w += xr.w;
            *(float4*)&ob[(size_t)grow * N_ + col0 + (t & 15) * 4] = v;
        }
        __syncthreads();
    }
}

extern "C" void kernel_launch(void* const* d_in, const int* in_sizes, int n_in,
                              void* d_out, int out_size, void* d_ws, size_t ws_size,
                              hipStream_t stream) {
    const float* x     = (const float*)d_in[0];
    const float* g1    = (const float*)d_in[1];
    const float* w_qkv = (const float*)d_in[2];
    const float* w_out = (const float*)d_in[3];
    const float* b_out = (const float*)d_in[4];
    const float* g2    = (const float*)d_in[5];
    float* out = (float*)d_out;
    char* ws = (char*)d_ws;

    ushort* Wp     = (ushort*)(ws + 0);          //    393216 B
    float*  ctxp   = (float*)(ws + 393216);      //  16777216 B (32 slices)
    float*  sums_p = (float*)(ws + 17170432);    //    524288 B
    ushort* Mm     = (ushort*)(ws + 17694720);   //   2097152 B
    float*  rinvws = (float*)(ws + 19791872);    //    262144 B (total ~20 MB)

    // allow >64KB dynamic LDS for k_kvctx (gfx950 has 160KB/CU)
    hipFuncSetAttribute((const void*)k_kvctx,
                        hipFuncAttributeMaxDynamicSharedMemorySize, 154112);

    k_prep<<<768, 256, 0, stream>>>(w_qkv, g1, Wp);
    k_kvctx<<<dim3(32, 16), 512, 154112, stream>>>(Wp, x, ctxp, sums_p, rinvws);
    k_fold<<<128, 256, 0, stream>>>(w_out, ctxp, sums_p, Mm);
    k_qfinal<<<dim3(64, 16), 1024, 0, stream>>>(Wp, Mm, b_out, g2, x, rinvws, out);
}

// Round 19
// 131.194 us; speedup vs baseline: 1.0556x; 1.0556x over previous
//
#include <hip/hip_runtime.h>
#include <math.h>

// LinearAttention: B=16, C=256, H=W=64 (N=4096), 8 heads x 32 dim.
// R1..R12: pipeline fusion ladder (299 -> 133.8us).
// R15: acc reuse + shared rinv. BEST = 132.0us (verified R15 + R17).
// R13/R14/R16: structural variants regressed.
// R18: 64-reg-clamp experiment: occupancy 37->75% as designed, but
//      spills (FETCH+27MB WRITE+49MB) and NO latency benefit -> k_qfinal
//      is bound by its serial intra-block phase chain, not occupancy.
// R19: exact R15/R17 restore (measured best, 132.0us).

#define B_ 16
#define C_ 256
#define N_ 4096
#define SCALE_ 0.17677669529663687f
#define EPS_ 1e-12f

typedef __attribute__((ext_vector_type(8))) short bf16x8;
typedef __attribute__((ext_vector_type(4))) float f32x4;

__device__ __forceinline__ ushort f2bf(float f) {
    union { float f; uint u; } x; x.f = f;
    uint r = (x.u + 0x7FFFu + ((x.u >> 16) & 1u)) >> 16;
    return (ushort)r;
}
__device__ __forceinline__ float bf2f(ushort s) {
    union { uint u; float f; } x; x.u = ((uint)s) << 16;
    return x.f;
}

// ---------------- K1: W' = w_qkv * g1 -> bf16 ----------------
__global__ __launch_bounds__(256) void k_prep(const float* __restrict__ w_qkv,
                                              const float* __restrict__ g1,
                                              ushort* __restrict__ Wp) {
    int o = blockIdx.x, c = threadIdx.x;
    Wp[(size_t)o * 256 + c] = f2bf(w_qkv[(size_t)o * 256 + c] * g1[c]);
}

// ---------------- K2: fused rnorm + kv-GEMM + exp + ctx partial -----------
// grid (32 n-slices, 16 b), 512 threads = 8 waves. Exports rinv[b][n].
// LDS 154112: Asub 20K | BQ 64K (xn then V) | P 64K | aux 2.5K. 1 blk/CU.
__global__ __launch_bounds__(512) void k_kvctx(const ushort* __restrict__ Wp,
                                               const float* __restrict__ x,
                                               float* __restrict__ ctxp,
                                               float* __restrict__ sums_p,
                                               float* __restrict__ rinvws) {
    extern __shared__ char lds[];
    ushort (*Asub)[40] = (ushort(*)[40])lds;          // 20480 B
    char* BQ = lds + 20480;                           // 65536 B
    char* P  = lds + 86016;                           // 65536 B
    float* sspA  = (float*)(lds + 151552);            //  2048 B
    float* rinvA = (float*)(lds + 153600);            //   512 B
    const int b = blockIdx.y, s = blockIdx.x;
    const int col0 = s * 128;
    const int t = threadIdx.x, l = t & 63, w = t >> 6;
    const int lr = l & 15, grp = l >> 4;
    const int wn = w & 3, wo = w >> 2;
    const float* xb = x + (size_t)b * C_ * N_ + col0;

    {   // prologue A: per-column sumsq (coalesced: lane = column)
        int col = t & 127, rg = t >> 7;
        float ss = 0.f;
        #pragma unroll 8
        for (int i = 0; i < 64; ++i) {
            float v = xb[(size_t)(rg * 64 + i) * N_ + col];
            ss += v * v;
        }
        sspA[rg * 128 + col] = ss;
    }
    __syncthreads();
    if (t < 128) {
        float rv = 16.f / fmaxf(sqrtf(sspA[t] + sspA[128 + t] + sspA[256 + t] + sspA[384 + t]), EPS_);
        rinvA[t] = rv;
        rinvws[(size_t)b * N_ + col0 + t] = rv;
    }
    __syncthreads();
    {   // prologue B: xn = bf16(x*rinv) -> BQ[col][c], byte ^= (col&7)<<4
        int col = t & 127, rg = t >> 7;
        float rv = rinvA[col];
        uint sw = (uint)((col & 7) << 4);
        #pragma unroll
        for (int i = 0; i < 16; ++i) {
            int c = rg * 64 + i * 4;
            uint2 pk;
            pk.x = (uint)f2bf(xb[(size_t)c * N_ + col] * rv)
                 | ((uint)f2bf(xb[(size_t)(c + 1) * N_ + col] * rv) << 16);
            pk.y = (uint)f2bf(xb[(size_t)(c + 2) * N_ + col] * rv)
                 | ((uint)f2bf(xb[(size_t)(c + 3) * N_ + col] * rv) << 16);
            *(uint2*)(BQ + (((uint)(col * 512 + c * 2)) ^ sw)) = pk;
        }
    }

    #pragma unroll
    for (int p = 0; p < 2; ++p) {
        f32x4 acc[2][8] = {};
        for (int k0 = 0; k0 < 256; k0 += 32) {
            {   // stage Wkv o-rows (p=0: Wp 256.., p=1: Wp 512..)
                int r = t >> 1, ko = (t & 1) * 16;
                const uint4* sa = (const uint4*)(Wp + (size_t)(256 + p * 256 + r) * 256 + k0 + ko);
                *(uint4*)&Asub[r][ko]     = sa[0];
                *(uint4*)&Asub[r][ko + 8] = sa[1];
            }
            __syncthreads();   // first iter also fences prologue BQ writes
            bf16x8 ax[2], bw[8];
            #pragma unroll
            for (int m = 0; m < 2; ++m) {
                int row = wn * 32 + m * 16 + lr;
                uint off = (uint)(row * 512 + (k0 + grp * 8) * 2) ^ (uint)((row & 7) << 4);
                ax[m] = *(const bf16x8*)(BQ + off);
            }
            #pragma unroll
            for (int nf = 0; nf < 8; ++nf)
                bw[nf] = *(const bf16x8*)&Asub[wo * 128 + nf * 16 + lr][grp * 8];
            #pragma unroll
            for (int m = 0; m < 2; ++m)
                #pragma unroll
                for (int nf = 0; nf < 8; ++nf)
                    acc[m][nf] = __builtin_amdgcn_mfma_f32_16x16x32_bf16(ax[m], bw[nf], acc[m][nf], 0, 0, 0);
            __syncthreads();
        }
        if (p == 0) {
            // P[d][n] = bf16(exp(logit)), rows 256B, byte ^= (d&7)<<4
            #pragma unroll
            for (int nf = 0; nf < 8; ++nf) {
                int d = wo * 128 + nf * 16 + lr;
                uint sw = (uint)((d & 7) << 4);
                #pragma unroll
                for (int m = 0; m < 2; ++m) {
                    int n0 = wn * 32 + m * 16 + grp * 4;
                    uint2 pk;
                    pk.x = (uint)f2bf(__expf(acc[m][nf][0])) | ((uint)f2bf(__expf(acc[m][nf][1])) << 16);
                    pk.y = (uint)f2bf(__expf(acc[m][nf][2])) | ((uint)f2bf(__expf(acc[m][nf][3])) << 16);
                    *(uint2*)(P + (((uint)(d * 256 + n0 * 2)) ^ sw)) = pk;
                }
            }
        } else {
            // V[e][n] overlaid onto BQ (xn dead after pass-1 trailing barrier)
            #pragma unroll
            for (int nf = 0; nf < 8; ++nf) {
                int e = wo * 128 + nf * 16 + lr;
                uint sw = (uint)((e & 7) << 4);
                #pragma unroll
                for (int m = 0; m < 2; ++m) {
                    int n0 = wn * 32 + m * 16 + grp * 4;
                    uint2 pk;
                    pk.x = (uint)f2bf(acc[m][nf][0]) | ((uint)f2bf(acc[m][nf][1]) << 16);
                    pk.y = (uint)f2bf(acc[m][nf][2]) | ((uint)f2bf(acc[m][nf][3]) << 16);
                    *(uint2*)(BQ + (((uint)(e * 256 + n0 * 2)) ^ sw)) = pk;
                }
            }
        }
    }
    __syncthreads();   // P and V fully visible

    // per-head ctx: wave = head
    const int h = w;
    f32x4 c3[2][2] = {};
    f32x4 cS[2] = {};
    bf16x8 ones;
    #pragma unroll
    for (int j = 0; j < 8; ++j) ones[j] = (short)0x3F80;   // bf16 1.0
    #pragma unroll
    for (int ks = 0; ks < 4; ++ks) {
        int n0 = ks * 32 + grp * 8;
        bf16x8 pA[2], vB[2];
        #pragma unroll
        for (int df = 0; df < 2; ++df) {
            int d = h * 32 + df * 16 + lr;
            pA[df] = *(const bf16x8*)(P + (((uint)(d * 256 + n0 * 2)) ^ ((uint)((d & 7) << 4))));
        }
        #pragma unroll
        for (int ef = 0; ef < 2; ++ef) {
            int e = h * 32 + ef * 16 + lr;
            vB[ef] = *(const bf16x8*)(BQ + (((uint)(e * 256 + n0 * 2)) ^ ((uint)((e & 7) << 4))));
        }
        #pragma unroll
        for (int df = 0; df < 2; ++df) {
            #pragma unroll
            for (int ef = 0; ef < 2; ++ef)
                c3[df][ef] = __builtin_amdgcn_mfma_f32_16x16x32_bf16(pA[df], vB[ef], c3[df][ef], 0, 0, 0);
            cS[df] = __builtin_amdgcn_mfma_f32_16x16x32_bf16(pA[df], ones, cS[df], 0, 0, 0);
        }
    }
    int bh = b * 8 + h;
    size_t base = ((size_t)s * 128 + bh) * 32;
    #pragma unroll
    for (int df = 0; df < 2; ++df) {
        #pragma unroll
        for (int ef = 0; ef < 2; ++ef)
            #pragma unroll
            for (int r = 0; r < 4; ++r)
                ctxp[(base + df * 16 + grp * 4 + r) * 32 + ef * 16 + lr] = c3[df][ef][r];
        if (lr == 0)
            #pragma unroll
            for (int r = 0; r < 4; ++r)
                sums_p[base + df * 16 + grp * 4 + r] = cS[df][r];
    }
}

// ---------------- K3: M[b][o][h*32+d] = SCALE/stot[d] * sum_e w_out.ctx ----
__global__ __launch_bounds__(256) void k_fold(const float* __restrict__ w_out,
                                              const float* __restrict__ ctxp,
                                              const float* __restrict__ sums_p,
                                              ushort* __restrict__ M) {
    __shared__ float cn[32][33];
    __shared__ float sinv[32];
    int bh = blockIdx.x;
    int b = bh >> 3, h = bh & 7;
    int t = threadIdx.x;
    if (t < 32) {
        float st = 0.f;
        #pragma unroll 8
        for (int s = 0; s < 32; ++s) st += sums_p[(size_t)(s * 128 + bh) * 32 + t];
        sinv[t] = SCALE_ / st;
    }
    #pragma unroll
    for (int i = t; i < 1024; i += 256) {
        int d = i >> 5, e = i & 31;
        float cv = 0.f;
        #pragma unroll 8
        for (int s = 0; s < 32; ++s)
            cv += ctxp[((size_t)(s * 128 + bh) * 32 + d) * 32 + e];
        cn[e][d] = cv;
    }
    __syncthreads();
    float wreg[32];
    const float* wr = w_out + (size_t)t * 256 + h * 32;
    #pragma unroll
    for (int e = 0; e < 32; e += 4) {
        float4 wv = *(const float4*)&wr[e];
        wreg[e] = wv.x; wreg[e + 1] = wv.y; wreg[e + 2] = wv.z; wreg[e + 3] = wv.w;
    }
    float acc[32] = {};
    #pragma unroll
    for (int e = 0; e < 32; ++e) {
        float we = wreg[e];
        #pragma unroll
        for (int d = 0; d < 32; ++d) acc[d] += we * cn[e][d];
    }
    ushort* Mrow = M + ((size_t)b * 256 + t) * 256 + h * 32;
    #pragma unroll
    for (int d = 0; d < 32; ++d) Mrow[d] = f2bf(acc[d] * sinv[d]);
}

// ---------------- K4: fused q-GEMM + softmax + M@q + epilogue -------------
// grid (64 coltiles, 16 b), 512 threads = 8 waves; wave = head = 32 rows.
// rinv loaded from ws (computed by k_kvctx). ONE MFMA accumulator array
// reused across GEMM1/GEMM2 (AGPR 32).
__global__ __launch_bounds__(512) void k_qfinal(const ushort* __restrict__ Wp,
                                                const ushort* __restrict__ M,
                                                const float* __restrict__ b_out,
                                                const float* __restrict__ g2,
                                                const float* __restrict__ x,
                                                const float* __restrict__ rinvws,
                                                float* __restrict__ out) {
    __shared__ __align__(16) char shmem[34816];  // BQ (32768B) then OUT overlay
    __shared__ float ss2[8][64];
    __shared__ float rinvq[64];
    ushort* BQ = (ushort*)shmem;    // swizzled: byte = (row*512+k*2) ^ ((row&7)<<4)
    float*  OUT = (float*)shmem;    // [128][68] f32 chunk buffer
    const int b = blockIdx.y, col0 = blockIdx.x * 64;
    const int t = threadIdx.x, l = t & 63, w = t >> 6;
    const int lr = l & 15, grp = l >> 4;
    const float* xb2 = x + (size_t)b * C_ * N_;

    if (t < 64) rinvq[t] = rinvws[(size_t)b * N_ + col0 + t];
    __syncthreads();
    {   // prologue: xn = bf16(x*rinv) -> BQ
        int col = t & 63, rg = t >> 6;
        float rv = rinvq[col];
        uint sw = (uint)((col & 7) << 4);
        #pragma unroll
        for (int i = 0; i < 8; ++i) {
            int c = rg * 32 + i * 4;
            uint2 pk;
            pk.x = (uint)f2bf(xb2[(size_t)c * N_ + col0 + col] * rv)
                 | ((uint)f2bf(xb2[(size_t)(c + 1) * N_ + col0 + col] * rv) << 16);
            pk.y = (uint)f2bf(xb2[(size_t)(c + 2) * N_ + col0 + col] * rv)
                 | ((uint)f2bf(xb2[(size_t)(c + 3) * N_ + col0 + col] * rv) << 16);
            *(uint2*)((char*)BQ + (((uint)(col * 512 + c * 2)) ^ sw)) = pk;
        }
    }
    __syncthreads();

    // ---- GEMM1: q = Wq @ xn (wave w -> rows w*32..w*32+31) ----
    f32x4 acc[2][4] = {};
    for (int k0 = 0; k0 < 256; k0 += 32) {
        bf16x8 af[2], bf[4];
        #pragma unroll
        for (int m = 0; m < 2; ++m)
            af[m] = *(const bf16x8*)(Wp + (size_t)(w * 32 + m * 16 + lr) * 256 + k0 + grp * 8);
        #pragma unroll
        for (int n = 0; n < 4; ++n) {
            int row = n * 16 + lr;
            uint off = (uint)(row * 512 + (k0 + grp * 8) * 2) ^ (uint)((row & 7) << 4);
            bf[n] = *(const bf16x8*)((const char*)BQ + off);
        }
        #pragma unroll
        for (int m = 0; m < 2; ++m)
            #pragma unroll
            for (int n = 0; n < 4; ++n)
                acc[m][n] = __builtin_amdgcn_mfma_f32_16x16x32_bf16(af[m], bf[n], acc[m][n], 0, 0, 0);
    }
    __syncthreads();   // all GEMM1 reads of BQ (xn) complete

    // ---- per-head softmax over d (wave = head), overlay q into BQ ----
    #pragma unroll
    for (int n = 0; n < 4; ++n) {
        float f[2][4];
        #pragma unroll
        for (int m = 0; m < 2; ++m)
            #pragma unroll
            for (int r = 0; r < 4; ++r) f[m][r] = acc[m][n][r];
        float mx = -1e30f;
        #pragma unroll
        for (int r = 0; r < 4; ++r) mx = fmaxf(mx, fmaxf(f[0][r], f[1][r]));
        mx = fmaxf(mx, __shfl_xor(mx, 16));
        mx = fmaxf(mx, __shfl_xor(mx, 32));
        float s = 0.f;
        #pragma unroll
        for (int r = 0; r < 4; ++r) {
            f[0][r] = __expf(f[0][r] - mx); s += f[0][r];
            f[1][r] = __expf(f[1][r] - mx); s += f[1][r];
        }
        s += __shfl_xor(s, 16); s += __shfl_xor(s, 32);
        float inv = 1.f / s;
        int cl = n * 16 + lr;
        #pragma unroll
        for (int m = 0; m < 2; ++m) {
            int d = w * 32 + m * 16 + grp * 4;
            uint2 pk;
            pk.x = (uint)f2bf(f[m][0] * inv) | ((uint)f2bf(f[m][1] * inv) << 16);
            pk.y = (uint)f2bf(f[m][2] * inv) | ((uint)f2bf(f[m][3] * inv) << 16);
            uint off = (uint)(cl * 512 + d * 2) ^ (uint)((cl & 7) << 4);
            *(uint2*)((char*)BQ + off) = pk;
        }
    }
    __syncthreads();   // all waves' q visible

    // ---- GEMM2: out = M @ q (REUSES acc registers) ----
    #pragma unroll
    for (int m = 0; m < 2; ++m)
        #pragma unroll
        for (int n = 0; n < 4; ++n)
            acc[m][n] = f32x4{0.f, 0.f, 0.f, 0.f};
    const ushort* Mb = M + (size_t)b * 256 * 256;
    for (int k0 = 0; k0 < 256; k0 += 32) {
        bf16x8 af[2], bq[4];
        #pragma unroll
        for (int m = 0; m < 2; ++m)
            af[m] = *(const bf16x8*)(Mb + (size_t)(w * 32 + m * 16 + lr) * 256 + k0 + grp * 8);
        #pragma unroll
        for (int n = 0; n < 4; ++n) {
            int row = n * 16 + lr;
            uint off = (uint)(row * 512 + (k0 + grp * 8) * 2) ^ (uint)((row & 7) << 4);
            bq[n] = *(const bf16x8*)((const char*)BQ + off);
        }
        #pragma unroll
        for (int m = 0; m < 2; ++m)
            #pragma unroll
            for (int n = 0; n < 4; ++n)
                acc[m][n] = __builtin_amdgcn_mfma_f32_16x16x32_bf16(af[m], bq[n], acc[m][n], 0, 0, 0);
    }

    // ---- epilogue: +b_out, column ssq, scale; LDS restage; stream out ----
    __syncthreads();   // BQ reads done (OUT overlay next)
    #pragma unroll
    for (int n = 0; n < 4; ++n) {
        float local = 0.f;
        #pragma unroll
        for (int m = 0; m < 2; ++m) {
            int obase = w * 32 + m * 16 + grp * 4;
            #pragma unroll
            for (int r = 0; r < 4; ++r) {
                float f = acc[m][n][r] + b_out[obase + r];
                acc[m][n][r] = f;
                local += f * f;
            }
        }
        local += __shfl_xor(local, 16);
        local += __shfl_xor(local, 32);
        if (grp == 0) ss2[w][n * 16 + lr] = local;
    }
    __syncthreads();
    #pragma unroll
    for (int n = 0; n < 4; ++n) {
        int cl = n * 16 + lr;
        float tot = ss2[0][cl] + ss2[1][cl] + ss2[2][cl] + ss2[3][cl]
                  + ss2[4][cl] + ss2[5][cl] + ss2[6][cl] + ss2[7][cl];
        float rs = 16.f / fmaxf(sqrtf(tot), EPS_);
        #pragma unroll
        for (int m = 0; m < 2; ++m) {
            int obase = w * 32 + m * 16 + grp * 4;
            #pragma unroll
            for (int r = 0; r < 4; ++r)
                acc[m][n][r] *= rs * g2[obase + r];
        }
    }
    float* ob = out + (size_t)b * C_ * N_;
    const int chunk = w >> 2;
    #pragma unroll
    for (int ch = 0; ch < 2; ++ch) {
        if (chunk == ch) {
            #pragma unroll
            for (int n = 0; n < 4; ++n) {
                int cl = n * 16 + lr;
                #pragma unroll
                for (int m = 0; m < 2; ++m) {
                    int rbase = (w & 3) * 32 + m * 16 + grp * 4;
                    #pragma unroll
                    for (int r = 0; r < 4; ++r)
                        OUT[(rbase + r) * 68 + cl] = acc[m][n][r];
                }
            }
        }
        __syncthreads();
        #pragma unroll
        for (int i = 0; i < 4; ++i) {
            int rowl = i * 32 + (t >> 4);
            int grow = ch * 128 + rowl;
            float4 v = *(float4*)&OUT[rowl * 68 + (t & 15) * 4];
            float4 xr = *(const float4*)&xb2[(size_t)grow * N_ + col0 + (t & 15) * 4];
            v.x += xr.x; v.y += xr.y; v.z += xr.z; v.w += xr.w;
            *(float4*)&ob[(size_t)grow * N_ + col0 + (t & 15) * 4] = v;
        }
        __syncthreads();
    }
}

extern "C" void kernel_launch(void* const* d_in, const int* in_sizes, int n_in,
                              void* d_out, int out_size, void* d_ws, size_t ws_size,
                              hipStream_t stream) {
    const float* x     = (const float*)d_in[0];
    const float* g1    = (const float*)d_in[1];
    const float* w_qkv = (const float*)d_in[2];
    const float* w_out = (const float*)d_in[3];
    const float* b_out = (const float*)d_in[4];
    const float* g2    = (const float*)d_in[5];
    float* out = (float*)d_out;
    char* ws = (char*)d_ws;

    ushort* Wp     = (ushort*)(ws + 0);          //    393216 B
    float*  ctxp   = (float*)(ws + 393216);      //  16777216 B (32 slices)
    float*  sums_p = (float*)(ws + 17170432);    //    524288 B
    ushort* Mm     = (ushort*)(ws + 17694720);   //   2097152 B
    float*  rinvws = (float*)(ws + 19791872);    //    262144 B (total ~20 MB)

    // allow >64KB dynamic LDS for k_kvctx (gfx950 has 160KB/CU)
    hipFuncSetAttribute((const void*)k_kvctx,
                        hipFuncAttributeMaxDynamicSharedMemorySize, 154112);

    k_prep<<<768, 256, 0, stream>>>(w_qkv, g1, Wp);
    k_kvctx<<<dim3(32, 16), 512, 154112, stream>>>(Wp, x, ctxp, sums_p, rinvws);
    k_fold<<<128, 256, 0, stream>>>(w_out, ctxp, sums_p, Mm);
    k_qfinal<<<dim3(64, 16), 512, 0, stream>>>(Wp, Mm, b_out, g2, x, rinvws, out);
}